// Round 11
// baseline (390.427 us; speedup 1.0000x reference)
//
#include <hip/hip_runtime.h>
#include <hip/hip_cooperative_groups.h>
#include <math.h>

namespace cg = cooperative_groups;

// Problem constants (MultiQueryAttention_20229295964202)
#define BATCH   4
#define SEQQ    2048
#define SEQK    2048
#define DMODEL  512
#define NHEADS  8
#define PDIM    64

#define QSCALE  0.18033688f   // 0.125 * log2(e); folded into Wq/bq; exp2 softmax

typedef __attribute__((ext_vector_type(8))) short short8;   // 8 bf16 (4 VGPRs)
typedef __attribute__((ext_vector_type(4))) float f32x4;    // MFMA C/D frag

__device__ __forceinline__ unsigned short f2bf(float x) {   // RNE
    unsigned u = __builtin_bit_cast(unsigned, x);
    u += 0x7fffu + ((u >> 16) & 1u);
    return (unsigned short)(u >> 16);
}
__device__ __forceinline__ unsigned pack_bf16_rh(float lo, float hi) {
    unsigned ul = __builtin_bit_cast(unsigned, lo) + 0x8000u;
    unsigned uh = __builtin_bit_cast(unsigned, hi) + 0x8000u;
    return __builtin_amdgcn_perm(uh, ul, 0x07060302u);  // [uh.hi16 : ul.hi16]
}
__device__ __forceinline__ float bf2f_lo(unsigned w) {
    return __builtin_bit_cast(float, w << 16);
}
__device__ __forceinline__ float bf2f_hi(unsigned w) {
    return __builtin_bit_cast(float, w & 0xFFFF0000u);
}
__device__ __forceinline__ float exp2_raw(float x) {        // raw v_exp_f32
    return __builtin_amdgcn_exp2f(x);
}
// async global->LDS, 16B/lane; lds base is wave-uniform, HW adds lane*16
__device__ __forceinline__ void glds16(const void* g, void* l) {
    __builtin_amdgcn_global_load_lds(
        (const __attribute__((address_space(1))) void*)g,
        (__attribute__((address_space(3))) void*)l, 16, 0, 0);
}

// ===========================================================================
// FUSED cooperative kernel: W-transpose -> qkv -> attn -> out_proj with
// grid.sync() between phases (replaces 4 dispatches + gaps).
// Shared LDS pool 37888 B -> 4 blocks/CU (151.5/160 KB).
// attn: P folded into current K tile (dead after S^T) + raw s_barrier
// (no vmcnt drain -> prefetch stays async); LDS 32 KB for that phase.
// ===========================================================================
__global__ __launch_bounds__(256, 4) void fused_kernel(
    const float* __restrict__ query, const float* __restrict__ store_,
    const float* __restrict__ Wq, const float* __restrict__ bq,
    const float* __restrict__ Wk, const float* __restrict__ bk,
    const float* __restrict__ Wv, const float* __restrict__ bv,
    const float* __restrict__ Wo, const float* __restrict__ bo,
    unsigned short* __restrict__ Wt,
    unsigned short* __restrict__ Qbuf, unsigned short* __restrict__ Kbuf,
    unsigned short* __restrict__ Vtbuf,
    unsigned int* __restrict__ rawO, float* __restrict__ Lraw,
    float* __restrict__ out)
{
    __shared__ unsigned short smem[18944];   // 37888 B, reused per phase
    cg::grid_group grid = cg::this_grid();

    const int tid = threadIdx.x;
    const int nblk = gridDim.x;
    const int wv = tid >> 6;
    const int lane = tid & 63;
    const int g = lane >> 4;
    const int c16 = lane & 15;
    const int c8 = c16 & 7;
    const int lrow = lane >> 3;
    const int lcol = ((lane & 7) ^ lrow) * 8;   // swizzled col (shorts)

    // ---- Phase 0: weight transpose (88 works) --------------------------
    for (int w = blockIdx.x; w < 88; w += nblk) {
        const int mat = w >> 3;
        const int k0 = (w & 7) << 6;
        const float sc = (mat < 8) ? QSCALE : 1.0f;
        const float* src = (mat < 8) ? (Wq + (size_t)mat * 32768)
                         : (mat == 8) ? Wk : (mat == 9) ? Wv : Wo;
        unsigned short* T = smem;              // [64][72]
#pragma unroll
        for (int it = 0; it < 4; ++it) {
            int flat = tid * 4 + 1024 * it;    // k*64 + n
            int k = flat >> 6, n = flat & 63;
            float4 v = *(const float4*)(src + (size_t)(k0 + k) * 64 + n);
            T[(n + 0) * 72 + k] = f2bf(v.x * sc);
            T[(n + 1) * 72 + k] = f2bf(v.y * sc);
            T[(n + 2) * 72 + k] = f2bf(v.z * sc);
            T[(n + 3) * 72 + k] = f2bf(v.w * sc);
        }
        __syncthreads();
        int n = tid >> 2, kk = (tid & 3) * 16;
        uint4 w0 = *(const uint4*)(&T[n * 72 + kk]);
        uint4 w1 = *(const uint4*)(&T[n * 72 + kk + 8]);
        *(uint4*)(Wt + (size_t)mat * 32768 + (size_t)n * 512 + k0 + kk) = w0;
        *(uint4*)(Wt + (size_t)mat * 32768 + (size_t)n * 512 + k0 + kk + 8) = w1;
        __syncthreads();
    }
    grid.sync();

    // ---- Phase 1: QKV projection (768 works) ---------------------------
    // slot 0 = heads 0-3, slot 1 = heads 4-7, slot 2 = K|V. 32-row tiles.
    for (int w = blockIdx.x; w < 768; w += nblk) {
        const int slot = w >> 8;
        const int row0 = (w & 255) * 32;
        const int b = row0 >> 11;
        const int s0 = row0 & 2047;
        const float* X = ((slot < 2) ? query : store_) + (size_t)row0 * 512;
        const unsigned short* Wbase = Wt + (size_t)(slot * 4) * 32768;
        unsigned short* Xt = smem;             // 2560 shorts ([32][72] / Vlds[64][40])
        unsigned short* Wtile = smem + 2560;   // 16384 shorts, XOR swizzle

        const int sm = wv & 1;
        const int uh = wv >> 1;
        f32x4 z = {0.f, 0.f, 0.f, 0.f};
        f32x4 acc[8] = {z, z, z, z, z, z, z, z};

        const int xrow = tid >> 3;
        const int xcol = (tid & 7) * 8;
        const int nwr = (slot < 2) ? 8 : 4;

        for (int k0 = 0; k0 < 512; k0 += 64) {
            float4 xa = *(const float4*)(X + (size_t)xrow * 512 + k0 + xcol);
            float4 xb = *(const float4*)(X + (size_t)xrow * 512 + k0 + xcol + 4);
            __syncthreads();
            for (int j = 0; j < nwr; ++j) {
                int rb = (nwr * wv + j) * 8;
                glds16(Wbase + (size_t)(rb + lrow) * 512 + k0 + lcol, Wtile + rb * 64);
            }
            ushort4 o0, o1;
            o0.x = f2bf(xa.x); o0.y = f2bf(xa.y); o0.z = f2bf(xa.z); o0.w = f2bf(xa.w);
            o1.x = f2bf(xb.x); o1.y = f2bf(xb.y); o1.z = f2bf(xb.z); o1.w = f2bf(xb.w);
            *(ushort4*)(&Xt[xrow * 72 + xcol]) = o0;
            *(ushort4*)(&Xt[xrow * 72 + xcol + 4]) = o1;
            __syncthreads();

            if (slot < 2) {
#pragma unroll
                for (int ks = 0; ks < 2; ++ks) {
                    short8 aX = *(const short8*)(&Xt[(16 * sm + c16) * 72 + 32 * ks + 8 * g]);
#pragma unroll
                    for (int uu = 0; uu < 8; ++uu) {
                        int u = 8 * uh + uu;
                        short8 bW = *(const short8*)(Wtile + (16 * u + c16) * 64 + ((4 * ks + g) ^ c8) * 8);
                        acc[uu] = __builtin_amdgcn_mfma_f32_16x16x32_bf16(aX, bW, acc[uu], 0, 0, 0);
                    }
                }
            } else {
#pragma unroll
                for (int ks = 0; ks < 2; ++ks) {
                    short8 aX = *(const short8*)(&Xt[(16 * sm + c16) * 72 + 32 * ks + 8 * g]);
#pragma unroll
                    for (int uu = 0; uu < 4; ++uu) {
                        int u = 4 * uh + uu;
                        short8 bW = *(const short8*)(Wtile + (16 * u + c16) * 64 + ((4 * ks + g) ^ c8) * 8);
                        acc[uu] = __builtin_amdgcn_mfma_f32_16x16x32_bf16(aX, bW, acc[uu], 0, 0, 0);
                    }
                }
            }
        }

        if (slot < 2) {
#pragma unroll
            for (int uu = 0; uu < 8; ++uu) {
                int u = 8 * uh + uu;
                int head = 4 * slot + (u >> 2);
                int pc = 16 * (u & 3) + c16;
                float bb = QSCALE * bq[head * 64 + pc];
                unsigned short* Y = Qbuf + ((size_t)(b * NHEADS + head) * SEQQ + s0) * PDIM;
#pragma unroll
                for (int r = 0; r < 4; ++r)
                    Y[(size_t)(16 * sm + 4 * g + r) * PDIM + pc] = f2bf(acc[uu][r] + bb);
            }
        } else {
            if (uh == 0) {
                unsigned short* Yk = Kbuf + (size_t)row0 * PDIM;
#pragma unroll
                for (int uu = 0; uu < 4; ++uu) {
                    float bb = bk[16 * uu + c16];
#pragma unroll
                    for (int r = 0; r < 4; ++r)
                        Yk[(size_t)(16 * sm + 4 * g + r) * PDIM + 16 * uu + c16] =
                            f2bf(acc[uu][r] + bb);
                }
            }
            __syncthreads();   // Xt MFMA reads done; reuse as Vlds[64][40]
            if (uh == 1) {
#pragma unroll
                for (int uu = 0; uu < 4; ++uu) {
                    int p = 16 * uu + c16;
                    float bb = bv[p];
#pragma unroll
                    for (int r = 0; r < 4; ++r)
                        Xt[p * 40 + 16 * sm + 4 * g + r] = f2bf(acc[uu][r] + bb);
                }
            }
            __syncthreads();
            int p = tid >> 2, soff = (tid & 3) * 8;
            uint4 wvv = *(const uint4*)(&Xt[p * 40 + soff]);
            *(uint4*)(Vtbuf + (size_t)b * PDIM * SEQK + (size_t)p * SEQK + s0 + soff) = wvv;
        }
        __syncthreads();   // smem reuse guard (grid-stride)
    }
    grid.sync();

    // ---- Phase 2: flash attention (1024 works) -------------------------
    for (int w = blockIdx.x; w < 1024; w += nblk) {
        const int qt = w & 15;
        const int h = (w >> 4) & 7;
        const int zz = w >> 7;
        const int split = zz & 1;
        const int b = zz >> 1;
        const int q0 = qt * 128;
        unsigned short* Kb = smem;             // [2][64*64] swizzled (+ Q stage)
        unsigned short* Vb = smem + 8192;      // [2][64*64] swizzled, [p][key]

        const unsigned short* Qp = Qbuf + ((size_t)(b * NHEADS + h) * SEQQ + q0) * PDIM;
#pragma unroll
        for (int j = 0; j < 4; ++j) {
            int rowblk = (4 * wv + j) * 8;
            glds16(Qp + (size_t)(rowblk + lrow) * PDIM + lcol, smem + rowblk * 64);
        }
        __syncthreads();
        short8 bQ[2][2];
#pragma unroll
        for (int y = 0; y < 2; ++y)
#pragma unroll
            for (int ks = 0; ks < 2; ++ks)
                bQ[y][ks] = *(const short8*)(smem + (32 * wv + 16 * y + c16) * 64 +
                                             ((4 * ks + g) ^ c8) * 8);
        __syncthreads();

        const unsigned short* Kp  = Kbuf  + (size_t)b * SEQK * PDIM + (size_t)split * 1024 * PDIM;
        const unsigned short* Vtp = Vtbuf + (size_t)b * PDIM * SEQK + split * 1024;
#pragma unroll
        for (int j = 0; j < 2; ++j) {
            int rb = (2 * wv + j) * 8;
            glds16(Kp + (size_t)(rb + lrow) * PDIM + lcol, Kb + rb * 64);
            glds16(Vtp + (size_t)(rb + lrow) * SEQK + lcol, Vb + rb * 64);
        }

        const short one_bf = (short)0x3F80;
        short8 vones = {one_bf, one_bf, one_bf, one_bf, one_bf, one_bf, one_bf, one_bf};
        f32x4 z = {0.f, 0.f, 0.f, 0.f};
        f32x4 oacc[2][4] = {{z, z, z, z}, {z, z, z, z}};
        f32x4 lacc[2] = {z, z};

        for (int i = 0; i < 16; ++i) {
            __syncthreads();   // drains glds(tile i)
            unsigned short* Kc = Kb + (i & 1) * 4096;
            const unsigned short* Vc = Vb + (i & 1) * 4096;
            if (i < 15) {
                int t0 = (i + 1) * 64;
                unsigned short* Kn = Kb + ((i + 1) & 1) * 4096;
                unsigned short* Vn = Vb + ((i + 1) & 1) * 4096;
#pragma unroll
                for (int j = 0; j < 2; ++j) {
                    int rb = (2 * wv + j) * 8;
                    glds16(Kp + (size_t)(t0 + rb + lrow) * PDIM + lcol, Kn + rb * 64);
                    glds16(Vtp + (size_t)(rb + lrow) * SEQK + t0 + lcol, Vn + rb * 64);
                }
            }

            // S^T = K_tile . Q^T
            f32x4 s0a[4] = {z, z, z, z};
            f32x4 s1a[4] = {z, z, z, z};
#pragma unroll
            for (int ks = 0; ks < 2; ++ks) {
#pragma unroll
                for (int t = 0; t < 4; ++t) {
                    short8 aK = *(const short8*)(Kc + (16 * t + c16) * 64 + ((4 * ks + g) ^ c8) * 8);
                    s0a[t] = __builtin_amdgcn_mfma_f32_16x16x32_bf16(aK, bQ[0][ks], s0a[t], 0, 0, 0);
                    s1a[t] = __builtin_amdgcn_mfma_f32_16x16x32_bf16(aK, bQ[1][ks], s1a[t], 0, 0, 0);
                }
            }

            // raw barrier (no vmcnt drain): all S^T LDS reads are complete
            // (each was waitcnt-consumed by an MFMA above), so the current K
            // tile is dead and safe to reuse as the P buffer. Prefetch glds
            // targets the OTHER half and keeps flying.
            __builtin_amdgcn_s_barrier();
            unsigned short* PsW = Kc + wv * 1024;   // wave-private rows 16wv..16wv+15

            short8 aP[2][2];
#pragma unroll
            for (int y = 0; y < 2; ++y) {
                const f32x4* sc = y ? s1a : s0a;
#pragma unroll
                for (int t = 0; t < 4; ++t) {
                    float p0 = exp2_raw(sc[t][0]);
                    float p1 = exp2_raw(sc[t][1]);
                    float p2 = exp2_raw(sc[t][2]);
                    float p3 = exp2_raw(sc[t][3]);
                    uint2 w2;
                    w2.x = pack_bf16_rh(p0, p1);
                    w2.y = pack_bf16_rh(p2, p3);
                    int phys = (2 * t + (g >> 1)) ^ c8;
                    *(uint2*)(PsW + c16 * 64 + phys * 8 + 4 * (g & 1)) = w2;
                }
#pragma unroll
                for (int ks = 0; ks < 2; ++ks)
                    aP[y][ks] = *(const short8*)(PsW + c16 * 64 + ((4 * ks + g) ^ c8) * 8);
            }

            // O += P @ V ; l += P @ ones
#pragma unroll
            for (int ks = 0; ks < 2; ++ks) {
                lacc[0] = __builtin_amdgcn_mfma_f32_16x16x32_bf16(aP[0][ks], vones, lacc[0], 0, 0, 0);
                lacc[1] = __builtin_amdgcn_mfma_f32_16x16x32_bf16(aP[1][ks], vones, lacc[1], 0, 0, 0);
#pragma unroll
                for (int u = 0; u < 4; ++u) {
                    short8 bV = *(const short8*)(Vc + (16 * u + c16) * 64 + ((4 * ks + g) ^ c8) * 8);
                    oacc[0][u] = __builtin_amdgcn_mfma_f32_16x16x32_bf16(aP[0][ks], bV, oacc[0][u], 0, 0, 0);
                    oacc[1][u] = __builtin_amdgcn_mfma_f32_16x16x32_bf16(aP[1][ks], bV, oacc[1][u], 0, 0, 0);
                }
            }
        }

        const int rawblk = ((b * NHEADS + h) * 16 + qt) * 2 + split;
        unsigned int* rbp = rawO + (size_t)rawblk * 4096;
#pragma unroll
        for (int y = 0; y < 2; ++y) {
#pragma unroll
            for (int u = 0; u < 4; ++u) {
                int slot = (wv * 2 + y) * 4 + u;
                uint2 w2;
                w2.x = pack_bf16_rh(oacc[y][u][0], oacc[y][u][1]);
                w2.y = pack_bf16_rh(oacc[y][u][2], oacc[y][u][3]);
                *(uint2*)(rbp + slot * 128 + lane * 2) = w2;
            }
            if (c16 == 0) {
#pragma unroll
                for (int r = 0; r < 4; ++r)
                    Lraw[(size_t)rawblk * 128 + 32 * wv + 16 * y + 4 * g + r] = lacc[y][r];
            }
        }
        __syncthreads();   // smem reuse guard (grid-stride)
    }
    grid.sync();

    // ---- Phase 3: output projection (256 works) ------------------------
    for (int w = blockIdx.x; w < 256; w += nblk) {
        unsigned short* XtS = smem;            // [32][136] = 4352 shorts
        unsigned short* WtS = smem + 4352;     // [64][136] = 8704 shorts
        const int row0 = w * 32;
        const int b = row0 >> 11;
        const int qt = (row0 & 2047) >> 7;
        const int off = row0 & 127;
        const unsigned short* W = Wt + (size_t)10 * 32768;
        const int sm = wv & 1;
        const int uh = wv >> 1;

        f32x4 z = {0.f, 0.f, 0.f, 0.f};
        f32x4 acc[2] = {z, z};

        for (int ch = 0; ch < 4; ++ch) {
            const int h0 = 2 * ch;
            uint4 wreg[4];
            int wrow[4], wkk[4];
#pragma unroll
            for (int it = 0; it < 4; ++it) {
                int flat = tid * 8 + 2048 * it;
                wrow[it] = flat >> 7; wkk[it] = flat & 127;
                int hh = wkk[it] >> 6;
                wreg[it] = *(const uint4*)(W + (size_t)wrow[it] * 512 + (h0 + hh) * 64 + (wkk[it] & 63));
            }
            unsigned short vv[2][2][4];
#pragma unroll
            for (int hh = 0; hh < 2; ++hh) {
                int h = h0 + hh;
                int rb0 = ((b * NHEADS + h) * 16 + qt) * 2;
                const unsigned int* p0 = rawO + (size_t)rb0 * 4096;
                const unsigned int* p1 = rawO + (size_t)(rb0 + 1) * 4096;
                const float* l0 = Lraw + (size_t)rb0 * 128;
                const float* l1 = Lraw + (size_t)(rb0 + 1) * 128;
#pragma unroll
                for (int sl = 0; sl < 2; ++sl) {
                    int s_local = 2 * wv + sl;
                    int m = s_local >> 2, u = s_local & 3;
                    int sglob = ((off >> 4) + m) * 4 + u;
                    uint2 a0 = *(const uint2*)(p0 + sglob * 128 + lane * 2);
                    uint2 a1 = *(const uint2*)(p1 + sglob * 128 + lane * 2);
                    float iv[4];
#pragma unroll
                    for (int r = 0; r < 4; ++r) {
                        int q = off + 16 * m + 4 * g + r;
                        iv[r] = 1.0f / (l0[q] + l1[q]);
                    }
                    vv[hh][sl][0] = f2bf((bf2f_lo(a0.x) + bf2f_lo(a1.x)) * iv[0]);
                    vv[hh][sl][1] = f2bf((bf2f_hi(a0.x) + bf2f_hi(a1.x)) * iv[1]);
                    vv[hh][sl][2] = f2bf((bf2f_lo(a0.y) + bf2f_lo(a1.y)) * iv[2]);
                    vv[hh][sl][3] = f2bf((bf2f_hi(a0.y) + bf2f_hi(a1.y)) * iv[3]);
                }
            }
            __syncthreads();
#pragma unroll
            for (int it = 0; it < 4; ++it)
                *(uint4*)(&WtS[wrow[it] * 136 + wkk[it]]) = wreg[it];
#pragma unroll
            for (int hh = 0; hh < 2; ++hh)
#pragma unroll
                for (int sl = 0; sl < 2; ++sl) {
                    int s_local = 2 * wv + sl;
                    int m = s_local >> 2, u = s_local & 3;
#pragma unroll
                    for (int r = 0; r < 4; ++r)
                        XtS[(16 * m + 4 * g + r) * 136 + hh * 64 + 16 * u + c16] = vv[hh][sl][r];
                }
            __syncthreads();

#pragma unroll
            for (int hh = 0; hh < 2; ++hh)
#pragma unroll
                for (int ks = 0; ks < 2; ++ks) {
                    short8 aX = *(const short8*)(&XtS[(16 * sm + c16) * 136 + hh * 64 + 32 * ks + 8 * g]);
#pragma unroll
                    for (int uu = 0; uu < 2; ++uu) {
                        int u = 2 * uh + uu;
                        short8 bW = *(const short8*)(&WtS[(16 * u + c16) * 136 + hh * 64 + 32 * ks + 8 * g]);
                        acc[uu] = __builtin_amdgcn_mfma_f32_16x16x32_bf16(aX, bW, acc[uu], 0, 0, 0);
                    }
                }
        }

#pragma unroll
        for (int uu = 0; uu < 2; ++uu) {
            int u = 2 * uh + uu;
            float bb = bo[16 * u + c16];
#pragma unroll
            for (int r = 0; r < 4; ++r)
                out[(size_t)(row0 + 16 * sm + 4 * g + r) * 64 + 16 * u + c16] = acc[uu][r] + bb;
        }
        __syncthreads();   // smem reuse guard (grid-stride)
    }
}

// ===========================================================================
// FALLBACK: R10's proven 4-dispatch path (used only if cooperative launch
// is unavailable; deterministic either way).
// ===========================================================================
__global__ __launch_bounds__(256) void convert_w_kernel(
    const float* __restrict__ Wq, const float* __restrict__ Wk,
    const float* __restrict__ Wv, const float* __restrict__ Wo,
    unsigned short* __restrict__ Wt)
{
    const int tid = threadIdx.x;
    const int mat = blockIdx.x >> 3;
    const int k0 = (blockIdx.x & 7) << 6;
    const float sc = (mat < 8) ? QSCALE : 1.0f;
    const float* src = (mat < 8) ? (Wq + (size_t)mat * 32768)
                     : (mat == 8) ? Wk : (mat == 9) ? Wv : Wo;
    __shared__ unsigned short T[64][72];
#pragma unroll
    for (int it = 0; it < 4; ++it) {
        int flat = tid * 4 + 1024 * it;
        int k = flat >> 6, n = flat & 63;
        float4 v = *(const float4*)(src + (size_t)(k0 + k) * 64 + n);
        T[n + 0][k] = f2bf(v.x * sc);
        T[n + 1][k] = f2bf(v.y * sc);
        T[n + 2][k] = f2bf(v.z * sc);
        T[n + 3][k] = f2bf(v.w * sc);
    }
    __syncthreads();
    int n = tid >> 2, kk = (tid & 3) * 16;
    uint4 w0 = *(const uint4*)(&T[n][kk]);
    uint4 w1 = *(const uint4*)(&T[n][kk + 8]);
    *(uint4*)(Wt + (size_t)mat * 32768 + (size_t)n * 512 + k0 + kk) = w0;
    *(uint4*)(Wt + (size_t)mat * 32768 + (size_t)n * 512 + k0 + kk + 8) = w1;
}

__global__ __launch_bounds__(256, 4) void qkv_proj_kernel(
    const float* __restrict__ query, const float* __restrict__ store_,
    const unsigned short* __restrict__ Wt,
    const float* __restrict__ bq, const float* __restrict__ bk,
    const float* __restrict__ bv,
    unsigned short* __restrict__ Qbuf, unsigned short* __restrict__ Kbuf,
    unsigned short* __restrict__ Vtbuf)
{
    __shared__ unsigned short Xt[2560];
    __shared__ unsigned short Wtile[256 * 64];

    const int slot = blockIdx.y;
    const int row0 = blockIdx.x * 32;
    const int b = row0 >> 11;
    const int s0 = row0 & 2047;
    const float* X = ((slot < 2) ? query : store_) + (size_t)row0 * 512;
    const unsigned short* Wbase = Wt + (size_t)(slot * 4) * 32768;

    const int tid = threadIdx.x;
    const int wv = tid >> 6, lane = tid & 63;
    const int g = lane >> 4, c16 = lane & 15;
    const int c8 = c16 & 7;
    const int sm = wv & 1;
    const int uh = wv >> 1;
    const int lrow = lane >> 3;
    const int lcol = ((lane & 7) ^ lrow) * 8;

    f32x4 z = {0.f, 0.f, 0.f, 0.f};
    f32x4 acc[8] = {z, z, z, z, z, z, z, z};

    const int xrow = tid >> 3;
    const int xcol = (tid & 7) * 8;
    const int nwr = (slot < 2) ? 8 : 4;

    for (int k0 = 0; k0 < 512; k0 += 64) {
        float4 xa = *(const float4*)(X + (size_t)xrow * 512 + k0 + xcol);
        float4 xb = *(const float4*)(X + (size_t)xrow * 512 + k0 + xcol + 4);
        __syncthreads();
        for (int j = 0; j < nwr; ++j) {
            int rb = (nwr * wv + j) * 8;
            glds16(Wbase + (size_t)(rb + lrow) * 512 + k0 + lcol, Wtile + rb * 64);
        }
        ushort4 o0, o1;
        o0.x = f2bf(xa.x); o0.y = f2bf(xa.y); o0.z = f2bf(xa.z); o0.w = f2bf(xa.w);
        o1.x = f2bf(xb.x); o1.y = f2bf(xb.y); o1.z = f2bf(xb.z); o1.w = f2bf(xb.w);
        *(ushort4*)(&Xt[xrow * 72 + xcol]) = o0;
        *(ushort4*)(&Xt[xrow * 72 + xcol + 4]) = o1;
        __syncthreads();

        if (slot < 2) {
#pragma unroll
            for (int ks = 0; ks < 2; ++ks) {
                short8 aX = *(const short8*)(&Xt[(16 * sm + c16) * 72 + 32 * ks + 8 * g]);
#pragma unroll
                for (int uu = 0; uu < 8; ++uu) {
                    int u = 8 * uh + uu;
                    short8 bW = *(const short8*)(Wtile + (16 * u + c16) * 64 + ((4 * ks + g) ^ c8) * 8);
                    acc[uu] = __builtin_amdgcn_mfma_f32_16x16x32_bf16(aX, bW, acc[uu], 0, 0, 0);
                }
            }
        } else {
#pragma unroll
            for (int ks = 0; ks < 2; ++ks) {
                short8 aX = *(const short8*)(&Xt[(16 * sm + c16) * 72 + 32 * ks + 8 * g]);
#pragma unroll
                for (int uu = 0; uu < 4; ++uu) {
                    int u = 4 * uh + uu;
                    short8 bW = *(const short8*)(Wtile + (16 * u + c16) * 64 + ((4 * ks + g) ^ c8) * 8);
                    acc[uu] = __builtin_amdgcn_mfma_f32_16x16x32_bf16(aX, bW, acc[uu], 0, 0, 0);
                }
            }
        }
    }

    if (slot < 2) {
#pragma unroll
        for (int uu = 0; uu < 8; ++uu) {
            int u = 8 * uh + uu;
            int head = 4 * slot + (u >> 2);
            int pc = 16 * (u & 3) + c16;
            float bb = QSCALE * bq[head * 64 + pc];
            unsigned short* Y = Qbuf + ((size_t)(b * NHEADS + head) * SEQQ + s0) * PDIM;
#pragma unroll
            for (int r = 0; r < 4; ++r)
                Y[(size_t)(16 * sm + 4 * g + r) * PDIM + pc] = f2bf(acc[uu][r] + bb);
        }
    } else {
        if (uh == 0) {
            unsigned short* Yk = Kbuf + (size_t)row0 * PDIM;
#pragma unroll
            for (int uu = 0; uu < 4; ++uu) {
                float bb = bk[16 * uu + c16];
#pragma unroll
                for (int r = 0; r < 4; ++r)
                    Yk[(size_t)(16 * sm + 4 * g + r) * PDIM + 16 * uu + c16] =
                        f2bf(acc[uu][r] + bb);
            }
        }
        __syncthreads();
        if (uh == 1) {
#pragma unroll
            for (int uu = 0; uu < 4; ++uu) {
                int p = 16 * uu + c16;
                float bb = bv[p];
#pragma unroll
                for (int r = 0; r < 4; ++r)
                    Xt[p * 40 + 16 * sm + 4 * g + r] = f2bf(acc[uu][r] + bb);
            }
        }
        __syncthreads();
        int p = tid >> 2, soff = (tid & 3) * 8;
        uint4 w = *(const uint4*)(&Xt[p * 40 + soff]);
        *(uint4*)(Vtbuf + (size_t)b * PDIM * SEQK + (size_t)p * SEQK + s0 + soff) = w;
    }
}

__global__ __launch_bounds__(256, 4) void attn_kernel(
    const unsigned short* __restrict__ Qbuf,
    const unsigned short* __restrict__ Kbuf,
    const unsigned short* __restrict__ Vtbuf,
    unsigned int* __restrict__ rawO, float* __restrict__ Lraw)
{
    __shared__ unsigned short smem[20480];
    unsigned short* Kb = smem;
    unsigned short* Vb = smem + 8192;
    unsigned short* Ps = smem + 16384;

    const int tid = threadIdx.x;
    const int wv = tid >> 6;
    const int lane = tid & 63;
    const int g = lane >> 4;
    const int c16 = lane & 15;
    const int c8 = c16 & 7;
    const int split = blockIdx.z & 1;
    const int b = blockIdx.z >> 1;
    const int h = blockIdx.y;
    const int qt = blockIdx.x;
    const int q0 = qt * 128;

    const int lrow = lane >> 3;
    const int lcol = ((lane & 7) ^ lrow) * 8;

    const unsigned short* Qp = Qbuf + ((size_t)(b * NHEADS + h) * SEQQ + q0) * PDIM;
#pragma unroll
    for (int j = 0; j < 4; ++j) {
        int rowblk = (4 * wv + j) * 8;
        glds16(Qp + (size_t)(rowblk + lrow) * PDIM + lcol, smem + rowblk * 64);
    }
    __syncthreads();

    short8 bQ[2][2];
#pragma unroll
    for (int y = 0; y < 2; ++y)
#pragma unroll
        for (int ks = 0; ks < 2; ++ks)
            bQ[y][ks] = *(const short8*)(smem + (32 * wv + 16 * y + c16) * 64 +
                                         ((4 * ks + g) ^ c8) * 8);
    __syncthreads();

    const unsigned short* Kp  = Kbuf  + (size_t)b * SEQK * PDIM + (size_t)split * 1024 * PDIM;
    const unsigned short* Vtp = Vtbuf + (size_t)b * PDIM * SEQK + split * 1024;

#pragma unroll
    for (int j = 0; j < 2; ++j) {
        int rb = (2 * wv + j) * 8;
        glds16(Kp + (size_t)(rb + lrow) * PDIM + lcol, Kb + rb * 64);
        glds16(Vtp + (size_t)(rb + lrow) * SEQK + lcol, Vb + rb * 64);
    }

    const short one_bf = (short)0x3F80;
    short8 vones = {one_bf, one_bf, one_bf, one_bf, one_bf, one_bf, one_bf, one_bf};

    f32x4 z = {0.f, 0.f, 0.f, 0.f};
    f32x4 oacc[2][4] = {{z, z, z, z}, {z, z, z, z}};
    f32x4 lacc[2] = {z, z};
    unsigned short* PsW = Ps + wv * 1024;

    for (int i = 0; i < 16; ++i) {
        __syncthreads();
        const unsigned short* Kc = Kb + (i & 1) * 4096;
        const unsigned short* Vc = Vb + (i & 1) * 4096;
        if (i < 15) {
            int t0 = (i + 1) * 64;
            unsigned short* Kn = Kb + ((i + 1) & 1) * 4096;
            unsigned short* Vn = Vb + ((i + 1) & 1) * 4096;
#pragma unroll
            for (int j = 0; j < 2; ++j) {
                int rb = (2 * wv + j) * 8;
                glds16(Kp + (size_t)(t0 + rb + lrow) * PDIM + lcol, Kn + rb * 64);
                glds16(Vtp + (size_t)(rb + lrow) * SEQK + t0 + lcol, Vn + rb * 64);
            }
        }

        f32x4 s0a[4] = {z, z, z, z};
        f32x4 s1a[4] = {z, z, z, z};
#pragma unroll
        for (int ks = 0; ks < 2; ++ks) {
#pragma unroll
            for (int t = 0; t < 4; ++t) {
                short8 aK = *(const short8*)(Kc + (16 * t + c16) * 64 + ((4 * ks + g) ^ c8) * 8);
                s0a[t] = __builtin_amdgcn_mfma_f32_16x16x32_bf16(aK, bQ[0][ks], s0a[t], 0, 0, 0);
                s1a[t] = __builtin_amdgcn_mfma_f32_16x16x32_bf16(aK, bQ[1][ks], s1a[t], 0, 0, 0);
            }
        }

        short8 aP[2][2];
#pragma unroll
        for (int y = 0; y < 2; ++y) {
            const f32x4* sc = y ? s1a : s0a;
#pragma unroll
            for (int t = 0; t < 4; ++t) {
                float p0 = exp2_raw(sc[t][0]);
                float p1 = exp2_raw(sc[t][1]);
                float p2 = exp2_raw(sc[t][2]);
                float p3 = exp2_raw(sc[t][3]);
                uint2 w2;
                w2.x = pack_bf16_rh(p0, p1);
                w2.y = pack_bf16_rh(p2, p3);
                int phys = (2 * t + (g >> 1)) ^ c8;
                *(uint2*)(PsW + c16 * 64 + phys * 8 + 4 * (g & 1)) = w2;
            }
#pragma unroll
            for (int ks = 0; ks < 2; ++ks)
                aP[y][ks] = *(const short8*)(PsW + c16 * 64 + ((4 * ks + g) ^ c8) * 8);
        }

#pragma unroll
        for (int ks = 0; ks < 2; ++ks) {
            lacc[0] = __builtin_amdgcn_mfma_f32_16x16x32_bf16(aP[0][ks], vones, lacc[0], 0, 0, 0);
            lacc[1] = __builtin_amdgcn_mfma_f32_16x16x32_bf16(aP[1][ks], vones, lacc[1], 0, 0, 0);
#pragma unroll
            for (int u = 0; u < 4; ++u) {
                short8 bV = *(const short8*)(Vc + (16 * u + c16) * 64 + ((4 * ks + g) ^ c8) * 8);
                oacc[0][u] = __builtin_amdgcn_mfma_f32_16x16x32_bf16(aP[0][ks], bV, oacc[0][u], 0, 0, 0);
                oacc[1][u] = __builtin_amdgcn_mfma_f32_16x16x32_bf16(aP[1][ks], bV, oacc[1][u], 0, 0, 0);
            }
        }
    }

    const int rawblk = ((b * NHEADS + h) * 16 + qt) * 2 + split;
    unsigned int* rbp = rawO + (size_t)rawblk * 4096;
#pragma unroll
    for (int y = 0; y < 2; ++y) {
#pragma unroll
        for (int u = 0; u < 4; ++u) {
            int slot = (wv * 2 + y) * 4 + u;
            uint2 w2;
            w2.x = pack_bf16_rh(oacc[y][u][0], oacc[y][u][1]);
            w2.y = pack_bf16_rh(oacc[y][u][2], oacc[y][u][3]);
            *(uint2*)(rbp + slot * 128 + lane * 2) = w2;
        }
        if (c16 == 0) {
#pragma unroll
            for (int r = 0; r < 4; ++r)
                Lraw[(size_t)rawblk * 128 + 32 * wv + 16 * y + 4 * g + r] = lacc[y][r];
        }
    }
}

__global__ __launch_bounds__(256) void out_proj_kernel(
    const unsigned int* __restrict__ rawO, const float* __restrict__ Lraw,
    const unsigned short* __restrict__ Wt, const float* __restrict__ bo,
    float* __restrict__ out)
{
    __shared__ unsigned short XtS[32 * 136];
    __shared__ unsigned short WtS[64 * 136];

    const int tid = threadIdx.x;
    const int wv = tid >> 6, lane = tid & 63;
    const int g = lane >> 4, c16 = lane & 15;
    const int row0 = blockIdx.x * 32;
    const int b = row0 >> 11;
    const int qt = (row0 & 2047) >> 7;
    const int off = row0 & 127;
    const unsigned short* W = Wt + (size_t)10 * 32768;
    const int sm = wv & 1;
    const int uh = wv >> 1;

    f32x4 z = {0.f, 0.f, 0.f, 0.f};
    f32x4 acc[2] = {z, z};

    for (int ch = 0; ch < 4; ++ch) {
        const int h0 = 2 * ch;
        uint4 wreg[4];
        int wrow[4], wkk[4];
#pragma unroll
        for (int it = 0; it < 4; ++it) {
            int flat = tid * 8 + 2048 * it;
            wrow[it] = flat >> 7; wkk[it] = flat & 127;
            int hh = wkk[it] >> 6;
            wreg[it] = *(const uint4*)(W + (size_t)wrow[it] * 512 + (h0 + hh) * 64 + (wkk[it] & 63));
        }
        unsigned short vv[2][2][4];
#pragma unroll
        for (int hh = 0; hh < 2; ++hh) {
            int h = h0 + hh;
            int rb0 = ((b * NHEADS + h) * 16 + qt) * 2;
            const unsigned int* p0 = rawO + (size_t)rb0 * 4096;
            const unsigned int* p1 = rawO + (size_t)(rb0 + 1) * 4096;
            const float* l0 = Lraw + (size_t)rb0 * 128;
            const float* l1 = Lraw + (size_t)(rb0 + 1) * 128;
#pragma unroll
            for (int sl = 0; sl < 2; ++sl) {
                int s_local = 2 * wv + sl;
                int m = s_local >> 2, u = s_local & 3;
                int sglob = ((off >> 4) + m) * 4 + u;
                uint2 a0 = *(const uint2*)(p0 + sglob * 128 + lane * 2);
                uint2 a1 = *(const uint2*)(p1 + sglob * 128 + lane * 2);
                float iv[4];
#pragma unroll
                for (int r = 0; r < 4; ++r) {
                    int q = off + 16 * m + 4 * g + r;
                    iv[r] = 1.0f / (l0[q] + l1[q]);
                }
                vv[hh][sl][0] = f2bf((bf2f_lo(a0.x) + bf2f_lo(a1.x)) * iv[0]);
                vv[hh][sl][1] = f2bf((bf2f_hi(a0.x) + bf2f_hi(a1.x)) * iv[1]);
                vv[hh][sl][2] = f2bf((bf2f_lo(a0.y) + bf2f_lo(a1.y)) * iv[2]);
                vv[hh][sl][3] = f2bf((bf2f_hi(a0.y) + bf2f_hi(a1.y)) * iv[3]);
            }
        }
        __syncthreads();
#pragma unroll
        for (int it = 0; it < 4; ++it)
            *(uint4*)(&WtS[wrow[it] * 136 + wkk[it]]) = wreg[it];
#pragma unroll
        for (int hh = 0; hh < 2; ++hh)
#pragma unroll
            for (int sl = 0; sl < 2; ++sl) {
                int s_local = 2 * wv + sl;
                int m = s_local >> 2, u = s_local & 3;
#pragma unroll
                for (int r = 0; r < 4; ++r)
                    XtS[(16 * m + 4 * g + r) * 136 + hh * 64 + 16 * u + c16] = vv[hh][sl][r];
            }
        __syncthreads();

#pragma unroll
        for (int hh = 0; hh < 2; ++hh)
#pragma unroll
            for (int ks = 0; ks < 2; ++ks) {
                short8 aX = *(const short8*)(&XtS[(16 * sm + c16) * 136 + hh * 64 + 32 * ks + 8 * g]);
#pragma unroll
                for (int uu = 0; uu < 2; ++uu) {
                    int u = 2 * uh + uu;
                    short8 bW = *(const short8*)(&WtS[(16 * u + c16) * 136 + hh * 64 + 32 * ks + 8 * g]);
                    acc[uu] = __builtin_amdgcn_mfma_f32_16x16x32_bf16(aX, bW, acc[uu], 0, 0, 0);
                }
            }
    }

#pragma unroll
    for (int uu = 0; uu < 2; ++uu) {
        int u = 2 * uh + uu;
        float bb = bo[16 * u + c16];
#pragma unroll
        for (int r = 0; r < 4; ++r)
            out[(size_t)(row0 + 16 * sm + 4 * g + r) * 64 + 16 * u + c16] = acc[uu][r] + bb;
    }
}

// ---------------------------------------------------------------------------
extern "C" void kernel_launch(void* const* d_in, const int* in_sizes, int n_in,
                              void* d_out, int out_size, void* d_ws, size_t ws_size,
                              hipStream_t stream) {
    const float* query  = (const float*)d_in[0];
    const float* store_ = (const float*)d_in[1];
    const float* Wq     = (const float*)d_in[2];
    const float* bq     = (const float*)d_in[3];
    const float* Wk     = (const float*)d_in[4];
    const float* bk     = (const float*)d_in[5];
    const float* Wv     = (const float*)d_in[6];
    const float* bv     = (const float*)d_in[7];
    const float* Wo     = (const float*)d_in[8];
    const float* bo     = (const float*)d_in[9];
    float* out = (float*)d_out;

    // workspace: Wt 0.7MB | Qbuf 8MB | Kbuf 1MB | Vt 1MB | rawO 16MB | Lraw 0.5MB
    unsigned short* Wt   = (unsigned short*)d_ws;
    unsigned short* Qbuf = Wt + (size_t)11 * 32768;
    unsigned short* Kbuf = Qbuf + (size_t)BATCH * NHEADS * SEQQ * PDIM;
    unsigned short* Vtbuf = Kbuf + (size_t)BATCH * SEQK * PDIM;
    unsigned int* rawO   = (unsigned int*)(Vtbuf + (size_t)BATCH * PDIM * SEQK);
    float* Lraw          = (float*)(rawO + (size_t)1024 * 4096);

    // Cooperative single-dispatch path (grid sized to guaranteed residency).
    int maxPerCU = 0;
    hipError_t qe = hipOccupancyMaxActiveBlocksPerMultiprocessor(&maxPerCU, fused_kernel, 256, 0);
    int nblk = 0;
    if (qe == hipSuccess && maxPerCU >= 1) {
        nblk = maxPerCU * 256;
        if (nblk > 1024) nblk = 1024;
    }
    hipError_t le = hipErrorUnknown;
    if (nblk >= 256) {
        void* args[] = {(void*)&query, (void*)&store_, (void*)&Wq, (void*)&bq,
                        (void*)&Wk, (void*)&bk, (void*)&Wv, (void*)&bv,
                        (void*)&Wo, (void*)&bo, (void*)&Wt, (void*)&Qbuf,
                        (void*)&Kbuf, (void*)&Vtbuf, (void*)&rawO, (void*)&Lraw,
                        (void*)&out};
        le = hipLaunchCooperativeKernel((void*)fused_kernel, dim3(nblk), dim3(256),
                                        args, 0, stream);
    }
    if (le != hipSuccess) {
        // Fallback: proven R10 4-dispatch path.
        convert_w_kernel<<<88, 256, 0, stream>>>(Wq, Wk, Wv, Wo, Wt);
        dim3 gProj((BATCH * SEQQ) / 32, 3);
        qkv_proj_kernel<<<gProj, 256, 0, stream>>>(query, store_, Wt, bq, bk, bv,
                                                   Qbuf, Kbuf, Vtbuf);
        dim3 gAttn(SEQQ / 128, NHEADS, BATCH * 2);
        attn_kernel<<<gAttn, 256, 0, stream>>>(Qbuf, Kbuf, Vtbuf, rawO, Lraw);
        out_proj_kernel<<<(BATCH * SEQQ) / 32, 256, 0, stream>>>(rawO, Lraw, Wt, bo, out);
    }
}